// Round 4
// baseline (235.511 us; speedup 1.0000x reference)
//
#include <hip/hip_runtime.h>

#define B_DIM 4096
#define L_DIM 4096
#define ROWS 16            // rows (= compute lanes) per block; 256 blocks = 1/CU
#define CH 64              // time steps per chunk
#define NCH (L_DIM / CH)   // 64 chunks
#define CF4 (CH / 4)       // 16 float4 per chunk

// One block = 1 wave; lanes 0..15 each own one full row. No LDS: each lane
// streams its row from global into double-buffered register chunks A/B
// (16 float4 each). asm memory barriers pin load issue points so the
// compiler can't sink the prefetch into the compute loop (round-3 failure).
__global__ __launch_bounds__(64, 1) void lif_kernel(const float* __restrict__ I,
                                                    float* __restrict__ out) {
    const int lane = threadIdx.x;
    if (lane >= ROWS) return;  // no barriers used; masked lanes just exit
    const int row = blockIdx.x * ROWS + lane;
    const float* g = I + (size_t)row * L_DIM;
    float* so = out + (size_t)row * L_DIM;

    float u = 0.f, cnt = 0.f, seen = 0.f, accS = 0.f, accF = 0.f;
    bool sp = false;
    const float cdiv = 0.05f;  // RN(1/20)

    // Exact IEEE step, compare off the critical path (proven absmax 0):
    //   q = RN(u/20) via Markstein (q0=u*c; rr=fma(-20,q0,u); q=fma(rr,c,q0))
    //   a = u - q; b = a + I'; u' = sp_prev ? I' : b   (reset path == I' exactly)
    // Cross-step chain: u -> q0 -> rr -> q -> a -> b -> cndmask = 6 VALU ops.
#define LIF_STEP(IIN, SOUT)                          \
    {                                                \
        float q0 = u * cdiv;                         \
        float rr = fmaf(-20.0f, q0, u);              \
        float q  = fmaf(rr, cdiv, q0);               \
        float a  = u - q;                            \
        float b  = a + (IIN);                        \
        u = sp ? (IIN) : b;                          \
        sp = (u >= 1.0f);                            \
        float sf = sp ? 1.0f : 0.0f;                 \
        cnt += sf;                                   \
        seen = fmaxf(seen, sf);                      \
        accS += cnt;                                 \
        accF += seen;                                \
        (SOUT) = sf;                                 \
    }

#define LOAD_CHUNK(R, src)                                   \
    {                                                        \
        const float4* p_ = (const float4*)(src);             \
        _Pragma("unroll")                                    \
        for (int j_ = 0; j_ < CF4; ++j_) R[j_] = p_[j_];     \
    }

#define COMPUTE_CHUNK(R, dst)                                \
    {                                                        \
        float* sd_ = (dst);                                  \
        _Pragma("unroll")                                    \
        for (int j4_ = 0; j4_ < CF4; ++j4_) {                \
            float4 iv_ = R[j4_];                             \
            float4 sv_;                                      \
            LIF_STEP(iv_.x, sv_.x)                           \
            LIF_STEP(iv_.y, sv_.y)                           \
            LIF_STEP(iv_.z, sv_.z)                           \
            LIF_STEP(iv_.w, sv_.w)                           \
            *(float4*)(sd_ + 4 * j4_) = sv_;                 \
        }                                                    \
    }

#define PIN() asm volatile("" ::: "memory")

    float4 A[CF4], Bb[CF4];
    LOAD_CHUNK(A, g)  // chunk 0
    PIN();
    for (int k = 0; k < NCH / 2; ++k) {
        LOAD_CHUNK(Bb, g + (2 * k + 1) * CH)   // prefetch odd chunk
        PIN();
        COMPUTE_CHUNK(A, so + (2 * k) * CH)    // compute even chunk
        if (k + 1 < NCH / 2) {
            LOAD_CHUNK(A, g + (2 * k + 2) * CH)  // prefetch next even chunk
        }
        PIN();
        COMPUTE_CHUNK(Bb, so + (2 * k + 1) * CH)  // compute odd chunk
    }

    // tsum = L*C - accS = sum_t t*s_t ; first = L - accF ; all exact ints < 2^24
    const float C = cnt;
    const float tsum = fmaf((float)L_DIM, C, -accS);
    const float first = (float)L_DIM - accF;
    const float soft = tsum / (C + 1e-6f);
    out[(size_t)B_DIM * L_DIM + row] = first;               // hard_latency
    out[(size_t)B_DIM * L_DIM + B_DIM + row] = soft;        // soft_latency

#undef LIF_STEP
#undef LOAD_CHUNK
#undef COMPUTE_CHUNK
#undef PIN
}

extern "C" void kernel_launch(void* const* d_in, const int* in_sizes, int n_in,
                              void* d_out, int out_size, void* d_ws, size_t ws_size,
                              hipStream_t stream) {
    const float* I = (const float*)d_in[0];
    float* out = (float*)d_out;
    (void)in_sizes; (void)n_in; (void)out_size; (void)d_ws; (void)ws_size;
    lif_kernel<<<B_DIM / ROWS, 64, 0, stream>>>(I, out);
}

// Round 5
// 134.380 us; speedup vs baseline: 1.7526x; 1.7526x over previous
//
#include <hip/hip_runtime.h>

#define B_DIM 4096
#define L_DIM 4096
#define SEGLEN 512
#define NSEG (L_DIM / SEGLEN)   // 8
#define WARM 512                // warm-up steps for seg>0 (coupling window)
#define CHUNK 64                // time steps per LDS chunk
#define CF4 (CHUNK / 4)         // 16 float4 per row per chunk
#define LSTRIDE 68              // LDS floats per row: 64 + 4 pad (16B-aligned, bank-uniform)

// ws layout: float C_acc[4096], float ts_acc[4096], int first_acc[4096]
__global__ __launch_bounds__(256) void init_kernel(float* wsf, int* wsi) {
    int i = blockIdx.x * 256 + threadIdx.x;
    if (i < 2 * B_DIM) wsf[i] = 0.f;
    if (i < B_DIM) wsi[i] = L_DIM;  // min-identity for first-spike
}

// Exact IEEE step (proven absmax 0): q = RN(u/20) via Markstein, compare off
// the dependent chain: u' = sp_prev ? I' : ((u - q) + I')   [reset == I' exactly]
#define LIF_CORE(IIN)                         \
    float q0 = u * cdiv;                      \
    float rr = fmaf(-20.0f, q0, u);           \
    float q  = fmaf(rr, cdiv, q0);            \
    float a  = u - q;                         \
    float b  = a + (IIN);                     \
    u = sp ? (IIN) : b;                       \
    sp = (u >= 1.0f);

#define WARM_STEP(IIN) { LIF_CORE(IIN) }

#define FULL_STEP(IIN, SOUT)                  \
    {                                         \
        LIF_CORE(IIN)                         \
        float sf = sp ? 1.0f : 0.0f;          \
        cnt += sf;                            \
        seen = fmaxf(seen, sf);               \
        accS += cnt;                          \
        accF += seen;                         \
        (SOUT) = sf;                          \
    }

// Block = 128 threads: wave 0 computes 64 rows (row-per-lane, one time
// segment), wave 1 stages global->LDS (coalesced), double-buffered,
// 1 barrier per chunk. blockIdx: seg = b>>6, rowBase = (b&63)*64.
__global__ __launch_bounds__(128, 1) void lif_kernel(const float* __restrict__ I,
                                                     float* __restrict__ out,
                                                     float* __restrict__ Cacc,
                                                     float* __restrict__ tsAcc,
                                                     int* __restrict__ firstAcc) {
    __shared__ __align__(16) float lds[2][64 * LSTRIDE];
    const int wid = threadIdx.x >> 6;
    const int lane = threadIdx.x & 63;
    const int seg = blockIdx.x >> 6;
    const int rowBase = (blockIdx.x & 63) * 64;
    const int t0 = seg * SEGLEN;
    const int start = (seg == 0) ? 0 : (t0 - WARM);
    const int nwarmCh = (seg == 0) ? 0 : (WARM / CHUNK);
    const int nch = nwarmCh + SEGLEN / CHUNK;

    if (wid == 1) {
        // ---- producer wave ----
        const int srow = lane >> 4, scol = lane & 15;
        const float* gb = I + (size_t)rowBase * L_DIM + start + scol * 4;
        {
            float* dst = &lds[0][0];
#pragma unroll
            for (int p = 0; p < 16; ++p) {
                const int r = 4 * p + srow;
                float4 v = *(const float4*)(gb + (size_t)r * L_DIM);
                *(float4*)&dst[r * LSTRIDE + scol * 4] = v;
            }
        }
        __syncthreads();
        for (int c = 0; c < nch; ++c) {
            if (c + 1 < nch) {
                const float* g = gb + (c + 1) * CHUNK;
                float* dst = &lds[(c + 1) & 1][0];
#pragma unroll
                for (int p = 0; p < 16; ++p) {
                    const int r = 4 * p + srow;
                    float4 v = *(const float4*)(g + (size_t)r * L_DIM);
                    *(float4*)&dst[r * LSTRIDE + scol * 4] = v;
                }
            }
            __syncthreads();
        }
    } else {
        // ---- compute wave ----
        const int row = rowBase + lane;
        float u = 0.f, cnt = 0.f, seen = 0.f, accS = 0.f, accF = 0.f;
        bool sp = false;
        const float cdiv = 0.05f;  // RN(1/20)
        float* so = out + (size_t)row * L_DIM + t0;

        __syncthreads();  // chunk 0 staged
        for (int c = 0; c < nch; ++c) {
            const float* buf = &lds[c & 1][lane * LSTRIDE];
            float4 R[CF4];
#pragma unroll
            for (int j = 0; j < CF4; ++j) R[j] = *(const float4*)(buf + 4 * j);

            if (c < nwarmCh) {
#pragma unroll
                for (int j = 0; j < CF4; ++j) {
                    float4 iv = R[j];
                    WARM_STEP(iv.x) WARM_STEP(iv.y) WARM_STEP(iv.z) WARM_STEP(iv.w)
                }
            } else {
                float* sd = so + (c - nwarmCh) * CHUNK;
#pragma unroll
                for (int j = 0; j < CF4; ++j) {
                    float4 iv = R[j];
                    float4 sv;
                    FULL_STEP(iv.x, sv.x) FULL_STEP(iv.y, sv.y)
                    FULL_STEP(iv.z, sv.z) FULL_STEP(iv.w, sv.w)
                    *(float4*)(sd + 4 * j) = sv;
                }
            }
            __syncthreads();
        }

        // per-segment partials (all exact integers < 2^24 -> float atomics exact)
        if (cnt > 0.f) {
            const int firstLocal = (int)((float)SEGLEN - accF);
            atomicMin(&firstAcc[row], t0 + firstLocal);
        }
        atomicAdd(&Cacc[row], cnt);
        // sum_t t_global*s = (t0+SEGLEN)*cnt - accS
        atomicAdd(&tsAcc[row], fmaf((float)(t0 + SEGLEN), cnt, -accS));
    }
}

__global__ __launch_bounds__(256) void fin_kernel(const float* __restrict__ Cacc,
                                                  const float* __restrict__ tsAcc,
                                                  const int* __restrict__ firstAcc,
                                                  float* __restrict__ out) {
    int r = blockIdx.x * 256 + threadIdx.x;
    if (r < B_DIM) {
        out[(size_t)B_DIM * L_DIM + r] = (float)firstAcc[r];
        out[(size_t)B_DIM * L_DIM + B_DIM + r] = tsAcc[r] / (Cacc[r] + 1e-6f);
    }
}

extern "C" void kernel_launch(void* const* d_in, const int* in_sizes, int n_in,
                              void* d_out, int out_size, void* d_ws, size_t ws_size,
                              hipStream_t stream) {
    const float* I = (const float*)d_in[0];
    float* out = (float*)d_out;
    float* wsf = (float*)d_ws;
    int* wsi = (int*)((float*)d_ws + 2 * B_DIM);
    (void)in_sizes; (void)n_in; (void)out_size; (void)ws_size;

    init_kernel<<<(2 * B_DIM + 255) / 256, 256, 0, stream>>>(wsf, wsi);
    lif_kernel<<<NSEG * 64, 128, 0, stream>>>(I, out, wsf, wsf + B_DIM, wsi);
    fin_kernel<<<(B_DIM + 255) / 256, 256, 0, stream>>>(wsf, wsf + B_DIM, wsi, out);
}